// Round 8
// baseline (50.141 us; speedup 1.0000x reference)
//
#include <hip/hip_runtime.h>
#include <math.h>

#define NROWS 128
#define KDIM  1024
#define ODIM  512
#define NB    32
#define BS    32

__device__ __forceinline__ int clz32(unsigned x) { return x ? __builtin_clz(x) : 32; }

// FROZEN (r7-verified): Signed-NAF truncation residual. Returns KEPT value of P
// (= product*4096), isum = intra + s, s = 32 - dbase.  h=P>>1 (arith), t=P+h.
// pos=t&~h, ng=h&~t; pos|ng == t^h; dropped = (pos&m)-(ng&m) == (t&m)-(h&m);
// kept = P - dropped.  DO NOT rewrite into high-mask forms ((t&~m)-(h&~m) or
// shift-align) — empirically miscompiles (r3/r4/r6, absmax 1.375).
__device__ __forceinline__ int naf_keep(int P, int isum) {
  const int h = P >> 1;
  const int t = P + h;
  const int lz = __builtin_clz(((unsigned)(t ^ h)) | 1u);
  int drop = isum - lz;
  drop = drop < 0 ? 0 : (drop > 31 ? 31 : drop);   // v_med3_i32
  const int m = (int)((1u << drop) - 1u);
  return P - ((t & m) - (h & m));
}

// ---------------- prep: quantize x rows -> packed (intra<<8 | int8 q), scales, log2(scales)
__global__ void prep_x_kernel(const float* __restrict__ x,
                              unsigned short* __restrict__ xp,
                              float* __restrict__ xs, float* __restrict__ lxs) {
  int tid = blockIdx.x * blockDim.x + threadIdx.x;
  if (tid >= NROWS * NB) return;
  int row = tid >> 5, blk = tid & 31;
  const float4* p = (const float4*)(x + (size_t)row * KDIM + blk * BS);
  float v[32];
  float m = 0.f;
#pragma unroll
  for (int i = 0; i < 8; ++i) {
    float4 f = p[i];
    v[4*i+0] = f.x; v[4*i+1] = f.y; v[4*i+2] = f.z; v[4*i+3] = f.w;
    m = fmaxf(m, fmaxf(fmaxf(fabsf(f.x), fabsf(f.y)), fmaxf(fabsf(f.z), fabsf(f.w))));
  }
  float scale = fmaxf(m / 1.984375f, 1e-30f);
  int q[32], e[32], emax = -60;
#pragma unroll
  for (int i = 0; i < 32; ++i) {
    float t = v[i] / scale * 64.0f;       // IEEE div + exact pow2 mul, matches ref
    int qi = (int)rintf(t);               // round-half-even, matches jnp.round
    q[i] = qi;
    int a = qi < 0 ? -qi : qi;
    int ei = a ? (31 - clz32((unsigned)a)) - 6 : -60;  // floor(log2(|q|/64)) exact
    e[i] = ei;
    emax = ei > emax ? ei : emax;
  }
  unsigned short u[32];
#pragma unroll
  for (int i = 0; i < 32; ++i)
    u[i] = (unsigned short)(((emax - e[i]) << 8) | (q[i] & 0xFF));
  uint4* dst = (uint4*)(xp + (size_t)row * KDIM + blk * BS);
#pragma unroll
  for (int i = 0; i < 4; ++i) {
    uint4 w4;
    w4.x = (unsigned)u[8*i+0] | ((unsigned)u[8*i+1] << 16);
    w4.y = (unsigned)u[8*i+2] | ((unsigned)u[8*i+3] << 16);
    w4.z = (unsigned)u[8*i+4] | ((unsigned)u[8*i+5] << 16);
    w4.w = (unsigned)u[8*i+6] | ((unsigned)u[8*i+7] << 16);
    dst[i] = w4;
  }
  xs[tid] = scale;
  lxs[tid] = (float)log2((double)scale);  // ~correctly-rounded fp32 log2
}

// ---------------- prep: quantize w rows -> int8 q, scales, log2(scales)
__global__ void prep_w_kernel(const float* __restrict__ wgt,
                              unsigned char* __restrict__ wq,
                              float* __restrict__ wsc, float* __restrict__ lws) {
  int tid = blockIdx.x * blockDim.x + threadIdx.x;
  if (tid >= ODIM * NB) return;
  int row = tid >> 5, blk = tid & 31;
  const float4* p = (const float4*)(wgt + (size_t)row * KDIM + blk * BS);
  float v[32];
  float m = 0.f;
#pragma unroll
  for (int i = 0; i < 8; ++i) {
    float4 f = p[i];
    v[4*i+0] = f.x; v[4*i+1] = f.y; v[4*i+2] = f.z; v[4*i+3] = f.w;
    m = fmaxf(m, fmaxf(fmaxf(fabsf(f.x), fabsf(f.y)), fmaxf(fabsf(f.z), fabsf(f.w))));
  }
  float scale = fmaxf(m / 1.984375f, 1e-30f);
  unsigned char c[32];
#pragma unroll
  for (int i = 0; i < 32; ++i) {
    float t = v[i] / scale * 64.0f;
    int qi = (int)rintf(t);
    c[i] = (unsigned char)(qi & 0xFF);
  }
  uint4* dst = (uint4*)(wq + (size_t)row * KDIM + blk * BS);
#pragma unroll
  for (int i = 0; i < 2; ++i) {
    uint4 w4;
    w4.x = (unsigned)c[16*i+ 0] | ((unsigned)c[16*i+ 1] << 8) | ((unsigned)c[16*i+ 2] << 16) | ((unsigned)c[16*i+ 3] << 24);
    w4.y = (unsigned)c[16*i+ 4] | ((unsigned)c[16*i+ 5] << 8) | ((unsigned)c[16*i+ 6] << 16) | ((unsigned)c[16*i+ 7] << 24);
    w4.z = (unsigned)c[16*i+ 8] | ((unsigned)c[16*i+ 9] << 8) | ((unsigned)c[16*i+10] << 16) | ((unsigned)c[16*i+11] << 24);
    w4.w = (unsigned)c[16*i+12] | ((unsigned)c[16*i+13] << 8) | ((unsigned)c[16*i+14] << 16) | ((unsigned)c[16*i+15] << 24);
    dst[i] = w4;
  }
  wsc[tid] = scale;
  lws[tid] = (float)log2((double)scale);
}

// ---------------- main: 8n x 16o tile, 8-way K-split, 1024 threads, 2 blocks/CU
__global__ __launch_bounds__(1024, 8)
void msd_main_kernel(const unsigned short* __restrict__ xp,
                     const unsigned char* __restrict__ wq,
                     const float* __restrict__ xs, const float* __restrict__ lxs,
                     const float* __restrict__ wsc, const float* __restrict__ lws,
                     const float* __restrict__ bias, float* __restrict__ out) {
  __shared__ unsigned short sx[8][1032];    // row stride 2064B -> banks 4*tn apart
  __shared__ unsigned char  swq[16][1040];  // 2-way conflict only (free)
  __shared__ float sxs[8][33], slx[8][33], sws[16][33], slw[16][33];
  __shared__ float sred[7 * 128];
  const int tid = threadIdx.x;
  const int n0 = blockIdx.x * 8, o0 = blockIdx.y * 16;

  // stage x tile: 8 rows x 1024 packed ushorts (1 uint4 per thread)
  {
    int r = tid >> 7, c = tid & 127;
    uint4 d = ((const uint4*)(xp + (size_t)(n0 + r) * KDIM))[c];
    *(uint4*)&sx[r][c * 8] = d;
  }
  // stage w tile: 16 rows x 1024 bytes (1 uint4 per thread)
  {
    int r = tid >> 6, c = tid & 63;
    uint4 d = ((const uint4*)(wq + (size_t)(o0 + r) * KDIM))[c];
    *(uint4*)&swq[r][c * 16] = d;
  }
  {
    int r = tid >> 5, b = tid & 31;
    if (tid < 256) {
      sxs[r][b] = xs[(n0 + r) * NB + b];
      slx[r][b] = lxs[(n0 + r) * NB + b];
    }
    if (tid < 512) {
      sws[r][b] = wsc[(o0 + r) * NB + b];
      slw[r][b] = lws[(o0 + r) * NB + b];
    }
  }
  __syncthreads();

  const int kh = tid >> 7, idx = tid & 127, tn = idx >> 4, to = idx & 15;

  // e_max over blocks (combined_e = floor(lx + lw)) — proven scalar path
  float emf = -1e30f;
#pragma unroll
  for (int b = 0; b < NB; ++b)
    emf = fmaxf(emf, floorf(slx[tn][b] + slw[to][b]));
  const int iemax = (int)emf;
  // s = 32 - dbase = 24 + min(iemax,0) - ice   (dbase = 8+max(emax,0)-emax+ice)
  const int sbase = 24 + (iemax < 0 ? iemax : 0);

  float facc = 0.f;
  const int b0 = kh * 4;
#pragma unroll 1
  for (int bb = 0; bb < 4; ++bb) {
    const int b = b0 + bb;
    const int ice = (int)floorf(slx[tn][b] + slw[to][b]);
    const int s = sbase - ice;
    uint4 xv0 = *(const uint4*)&sx[tn][b * 32 + 0];
    uint4 xv1 = *(const uint4*)&sx[tn][b * 32 + 8];
    uint4 xv2 = *(const uint4*)&sx[tn][b * 32 + 16];
    uint4 xv3 = *(const uint4*)&sx[tn][b * 32 + 24];
    unsigned xd[16] = {xv0.x, xv0.y, xv0.z, xv0.w, xv1.x, xv1.y, xv1.z, xv1.w,
                       xv2.x, xv2.y, xv2.z, xv2.w, xv3.x, xv3.y, xv3.z, xv3.w};
    uint4 wv0 = *(const uint4*)&swq[to][b * 32];
    uint4 wv1 = *(const uint4*)&swq[to][b * 32 + 16];
    unsigned wb[8] = {wv0.x, wv0.y, wv0.z, wv0.w, wv1.x, wv1.y, wv1.z, wv1.w};
    int bacc = 0;
#pragma unroll
    for (int j = 0; j < 16; ++j) {        // 2 elements per x-dword
      const unsigned xw = xd[j];
      const unsigned ww = wb[j >> 1];
      const int ix0 = ((int)(xw << 24)) >> 24;          // bfe_i32
      const int in0 = (int)((xw >> 8) & 0xFFu);         // bfe_u32
      const int ix1 = ((int)(xw << 8)) >> 24;
      const int in1 = (int)(xw >> 24);
      int iw0, iw1;
      if (j & 1) { iw0 = ((int)(ww << 8)) >> 24; iw1 = ((int)ww) >> 24; }
      else       { iw0 = ((int)(ww << 24)) >> 24; iw1 = ((int)(ww << 16)) >> 24; }
      bacc += naf_keep(__mul24(ix0, iw0), in0 + s);     // |ix|,|iw| <= 127: exact
      bacc += naf_keep(__mul24(ix1, iw1), in1 + s);
    }
    facc += sxs[tn][b] * sws[to][b] * (float)bacc;  // exact: block_dot = bacc/4096
  }

  if (kh) sred[(kh - 1) * 128 + idx] = facc;
  __syncthreads();
  if (!kh) {
    float r = facc;
#pragma unroll
    for (int p = 0; p < 7; ++p) r += sred[p * 128 + idx];
    r = r * (1.0f / 4096.0f) + bias[o0 + to];
    out[(size_t)(n0 + tn) * ODIM + (o0 + to)] = r;
  }
}

extern "C" void kernel_launch(void* const* d_in, const int* in_sizes, int n_in,
                              void* d_out, int out_size, void* d_ws, size_t ws_size,
                              hipStream_t stream) {
  const float* x    = (const float*)d_in[0];
  const float* wgt  = (const float*)d_in[1];
  const float* bias = (const float*)d_in[2];
  float* out = (float*)d_out;
  char* ws = (char*)d_ws;
  // workspace layout (16B-aligned)
  unsigned short* xp  = (unsigned short*)(ws + 0);       // 128*1024*2 = 262144
  unsigned char*  wq  = (unsigned char*)(ws + 262144);   // 512*1024   = 524288
  float* xs  = (float*)(ws + 786432);                    // 128*32*4   = 16384
  float* lxs = (float*)(ws + 802816);                    // 16384
  float* wsc = (float*)(ws + 819200);                    // 512*32*4   = 65536
  float* lws = (float*)(ws + 884736);                    // 65536 -> total 950272

  hipLaunchKernelGGL(prep_x_kernel, dim3(16), dim3(256), 0, stream, x, xp, xs, lxs);
  hipLaunchKernelGGL(prep_w_kernel, dim3(64), dim3(256), 0, stream, wgt, wq, wsc, lws);
  hipLaunchKernelGGL(msd_main_kernel, dim3(16, 32), dim3(1024), 0, stream,
                     xp, wq, xs, lxs, wsc, lws, bias, out);
}

// Round 9
// 44.861 us; speedup vs baseline: 1.1177x; 1.1177x over previous
//
#include <hip/hip_runtime.h>
#include <math.h>

#define NROWS 128
#define KDIM  1024
#define ODIM  512
#define NB    32
#define BS    32

__device__ __forceinline__ int clz32(unsigned x) { return x ? __builtin_clz(x) : 32; }

// FROZEN STRUCTURE (r7/r8-verified): kept = P - ((t&m)-(h&m)), m = 2^drop - 1.
// h=P>>1 (arith), t=P+h; signed NAF digit masks pos=t&~h, ng=h&~t; pos|ng==t^h;
// dropped = (pos&m)-(ng&m) == (t&m)-(h&m).  DO NOT rewrite into high-mask forms
// ((t&~m)-(h&~m) / shift-align) — empirically miscompiles (r3/r4/r6, absmax 1.375,
// consistent with a peephole folding (t&M)-(h&M) -> (t-h)&M).  This round: the two
// low-mask ANDs are expressed as v_bfe_u32 intrinsics (bit-identical: offset 0,
// width=drop in [0,31]; width 0 -> 0; zero-ext == (int)(t&m) since m<2^31).
__device__ __forceinline__ int naf_keep(int P, int isum) {
  const int h = P >> 1;
  const int t = P + h;
  const int lz = __builtin_clz(((unsigned)(t ^ h)) | 1u);
  int drop = isum - lz;
  drop = drop < 0 ? 0 : (drop > 31 ? 31 : drop);   // v_med3_i32
  return P - ((int)__builtin_amdgcn_ubfe(t, 0, drop)
            - (int)__builtin_amdgcn_ubfe(h, 0, drop));
}

// ---------------- merged prep: blocks 0..15 quantize x, 16..79 quantize w
__global__ void prep_kernel(const float* __restrict__ x, const float* __restrict__ wgt,
                            unsigned short* __restrict__ xp, unsigned char* __restrict__ wq,
                            float* __restrict__ xs, float* __restrict__ lxs,
                            float* __restrict__ wsc, float* __restrict__ lws) {
  const int bid = blockIdx.x;
  if (bid < 16) {
    // ---- x path: identical math to r8's prep_x_kernel ----
    int tid = bid * 256 + threadIdx.x;            // 0..4095 = 128 rows x 32 blocks
    int row = tid >> 5, blk = tid & 31;
    const float4* p = (const float4*)(x + (size_t)row * KDIM + blk * BS);
    float v[32];
    float m = 0.f;
#pragma unroll
    for (int i = 0; i < 8; ++i) {
      float4 f = p[i];
      v[4*i+0] = f.x; v[4*i+1] = f.y; v[4*i+2] = f.z; v[4*i+3] = f.w;
      m = fmaxf(m, fmaxf(fmaxf(fabsf(f.x), fabsf(f.y)), fmaxf(fabsf(f.z), fabsf(f.w))));
    }
    float scale = fmaxf(m / 1.984375f, 1e-30f);
    int q[32], e[32], emax = -60;
#pragma unroll
    for (int i = 0; i < 32; ++i) {
      float t = v[i] / scale * 64.0f;     // IEEE div + exact pow2 mul, matches ref
      int qi = (int)rintf(t);             // round-half-even, matches jnp.round
      q[i] = qi;
      int a = qi < 0 ? -qi : qi;
      int ei = a ? (31 - clz32((unsigned)a)) - 6 : -60;
      e[i] = ei;
      emax = ei > emax ? ei : emax;
    }
    unsigned short u[32];
#pragma unroll
    for (int i = 0; i < 32; ++i)
      u[i] = (unsigned short)(((emax - e[i]) << 8) | (q[i] & 0xFF));
    uint4* dst = (uint4*)(xp + (size_t)row * KDIM + blk * BS);
#pragma unroll
    for (int i = 0; i < 4; ++i) {
      uint4 w4;
      w4.x = (unsigned)u[8*i+0] | ((unsigned)u[8*i+1] << 16);
      w4.y = (unsigned)u[8*i+2] | ((unsigned)u[8*i+3] << 16);
      w4.z = (unsigned)u[8*i+4] | ((unsigned)u[8*i+5] << 16);
      w4.w = (unsigned)u[8*i+6] | ((unsigned)u[8*i+7] << 16);
      dst[i] = w4;
    }
    xs[tid] = scale;
    lxs[tid] = (float)log2((double)scale);
  } else {
    // ---- w path: identical math to r8's prep_w_kernel ----
    int tid = (bid - 16) * 256 + threadIdx.x;     // 0..16383 = 512 rows x 32 blocks
    int row = tid >> 5, blk = tid & 31;
    const float4* p = (const float4*)(wgt + (size_t)row * KDIM + blk * BS);
    float v[32];
    float m = 0.f;
#pragma unroll
    for (int i = 0; i < 8; ++i) {
      float4 f = p[i];
      v[4*i+0] = f.x; v[4*i+1] = f.y; v[4*i+2] = f.z; v[4*i+3] = f.w;
      m = fmaxf(m, fmaxf(fmaxf(fabsf(f.x), fabsf(f.y)), fmaxf(fabsf(f.z), fabsf(f.w))));
    }
    float scale = fmaxf(m / 1.984375f, 1e-30f);
    unsigned char c[32];
#pragma unroll
    for (int i = 0; i < 32; ++i) {
      float t = v[i] / scale * 64.0f;
      int qi = (int)rintf(t);
      c[i] = (unsigned char)(qi & 0xFF);
    }
    uint4* dst = (uint4*)(wq + (size_t)row * KDIM + blk * BS);
#pragma unroll
    for (int i = 0; i < 2; ++i) {
      uint4 w4;
      w4.x = (unsigned)c[16*i+ 0] | ((unsigned)c[16*i+ 1] << 8) | ((unsigned)c[16*i+ 2] << 16) | ((unsigned)c[16*i+ 3] << 24);
      w4.y = (unsigned)c[16*i+ 4] | ((unsigned)c[16*i+ 5] << 8) | ((unsigned)c[16*i+ 6] << 16) | ((unsigned)c[16*i+ 7] << 24);
      w4.z = (unsigned)c[16*i+ 8] | ((unsigned)c[16*i+ 9] << 8) | ((unsigned)c[16*i+10] << 16) | ((unsigned)c[16*i+11] << 24);
      w4.w = (unsigned)c[16*i+12] | ((unsigned)c[16*i+13] << 8) | ((unsigned)c[16*i+14] << 16) | ((unsigned)c[16*i+15] << 24);
      dst[i] = w4;
    }
    wsc[tid] = scale;
    lws[tid] = (float)log2((double)scale);
  }
}

// ---------------- main: 8n x 16o tile, 8-way K-split, 1024 threads, 2 blocks/CU
__global__ __launch_bounds__(1024, 8)
void msd_main_kernel(const unsigned short* __restrict__ xp,
                     const unsigned char* __restrict__ wq,
                     const float* __restrict__ xs, const float* __restrict__ lxs,
                     const float* __restrict__ wsc, const float* __restrict__ lws,
                     const float* __restrict__ bias, float* __restrict__ out) {
  __shared__ unsigned short sx[8][1032];    // row stride 2064B -> banks 4*tn apart
  __shared__ unsigned char  swq[16][1040];  // 2-way conflict only (free)
  __shared__ float sxs[8][33], slx[8][33], sws[16][33], slw[16][33];
  __shared__ float sred[7 * 128];
  const int tid = threadIdx.x;
  const int n0 = blockIdx.x * 8, o0 = blockIdx.y * 16;

  // stage x tile: 8 rows x 1024 packed ushorts (1 uint4 per thread)
  {
    int r = tid >> 7, c = tid & 127;
    uint4 d = ((const uint4*)(xp + (size_t)(n0 + r) * KDIM))[c];
    *(uint4*)&sx[r][c * 8] = d;
  }
  // stage w tile: 16 rows x 1024 bytes (1 uint4 per thread)
  {
    int r = tid >> 6, c = tid & 63;
    uint4 d = ((const uint4*)(wq + (size_t)(o0 + r) * KDIM))[c];
    *(uint4*)&swq[r][c * 16] = d;
  }
  {
    int r = tid >> 5, b = tid & 31;
    if (tid < 256) {
      sxs[r][b] = xs[(n0 + r) * NB + b];
      slx[r][b] = lxs[(n0 + r) * NB + b];
    }
    if (tid < 512) {
      sws[r][b] = wsc[(o0 + r) * NB + b];
      slw[r][b] = lws[(o0 + r) * NB + b];
    }
  }
  __syncthreads();

  const int kh = tid >> 7, idx = tid & 127, tn = idx >> 4, to = idx & 15;

  // e_max over blocks (combined_e = floor(lx + lw)) — proven scalar path
  float emf = -1e30f;
#pragma unroll
  for (int b = 0; b < NB; ++b)
    emf = fmaxf(emf, floorf(slx[tn][b] + slw[to][b]));
  const int iemax = (int)emf;
  // s = 32 - dbase = 24 + min(iemax,0) - ice   (dbase = 8+max(emax,0)-emax+ice)
  const int sbase = 24 + (iemax < 0 ? iemax : 0);

  float facc = 0.f;
  const int b0 = kh * 4;
#pragma unroll 1
  for (int bb = 0; bb < 4; ++bb) {
    const int b = b0 + bb;
    const int ice = (int)floorf(slx[tn][b] + slw[to][b]);
    const int s = sbase - ice;
    uint4 xv0 = *(const uint4*)&sx[tn][b * 32 + 0];
    uint4 xv1 = *(const uint4*)&sx[tn][b * 32 + 8];
    uint4 xv2 = *(const uint4*)&sx[tn][b * 32 + 16];
    uint4 xv3 = *(const uint4*)&sx[tn][b * 32 + 24];
    unsigned xd[16] = {xv0.x, xv0.y, xv0.z, xv0.w, xv1.x, xv1.y, xv1.z, xv1.w,
                       xv2.x, xv2.y, xv2.z, xv2.w, xv3.x, xv3.y, xv3.z, xv3.w};
    uint4 wv0 = *(const uint4*)&swq[to][b * 32];
    uint4 wv1 = *(const uint4*)&swq[to][b * 32 + 16];
    unsigned wb[8] = {wv0.x, wv0.y, wv0.z, wv0.w, wv1.x, wv1.y, wv1.z, wv1.w};
    int bacc = 0;
#pragma unroll
    for (int j = 0; j < 16; ++j) {        // 2 elements per x-dword
      const unsigned xw = xd[j];
      const unsigned ww = wb[j >> 1];
      const int ix0 = __builtin_amdgcn_sbfe((int)xw, 0, 8);      // v_bfe_i32
      const int in0 = (int)__builtin_amdgcn_ubfe(xw, 8, 8);      // v_bfe_u32
      const int ix1 = __builtin_amdgcn_sbfe((int)xw, 16, 8);
      const int in1 = (int)(xw >> 24);
      int iw0, iw1;
      if (j & 1) { iw0 = __builtin_amdgcn_sbfe((int)ww, 16, 8);
                   iw1 = __builtin_amdgcn_sbfe((int)ww, 24, 8); }
      else       { iw0 = __builtin_amdgcn_sbfe((int)ww, 0, 8);
                   iw1 = __builtin_amdgcn_sbfe((int)ww, 8, 8); }
      bacc += naf_keep(__mul24(ix0, iw0), in0 + s);     // |ix|,|iw| <= 127: exact
      bacc += naf_keep(__mul24(ix1, iw1), in1 + s);
    }
    facc += sxs[tn][b] * sws[to][b] * (float)bacc;  // exact: block_dot = bacc/4096
  }

  if (kh) sred[(kh - 1) * 128 + idx] = facc;
  __syncthreads();
  if (!kh) {
    float r = facc;
#pragma unroll
    for (int p = 0; p < 7; ++p) r += sred[p * 128 + idx];
    r = r * (1.0f / 4096.0f) + bias[o0 + to];
    out[(size_t)(n0 + tn) * ODIM + (o0 + to)] = r;
  }
}

extern "C" void kernel_launch(void* const* d_in, const int* in_sizes, int n_in,
                              void* d_out, int out_size, void* d_ws, size_t ws_size,
                              hipStream_t stream) {
  const float* x    = (const float*)d_in[0];
  const float* wgt  = (const float*)d_in[1];
  const float* bias = (const float*)d_in[2];
  float* out = (float*)d_out;
  char* ws = (char*)d_ws;
  // workspace layout (16B-aligned)
  unsigned short* xp  = (unsigned short*)(ws + 0);       // 128*1024*2 = 262144
  unsigned char*  wq  = (unsigned char*)(ws + 262144);   // 512*1024   = 524288
  float* xs  = (float*)(ws + 786432);                    // 128*32*4   = 16384
  float* lxs = (float*)(ws + 802816);                    // 16384
  float* wsc = (float*)(ws + 819200);                    // 512*32*4   = 65536
  float* lws = (float*)(ws + 884736);                    // 65536 -> total 950272

  hipLaunchKernelGGL(prep_kernel, dim3(80), dim3(256), 0, stream,
                     x, wgt, xp, wq, xs, lxs, wsc, lws);
  hipLaunchKernelGGL(msd_main_kernel, dim3(16, 32), dim3(1024), 0, stream,
                     xp, wq, xs, lxs, wsc, lws, bias, out);
}